// Round 17
// baseline (1249.407 us; speedup 1.0000x reference)
//
#include <hip/hip_runtime.h>
#include <hip/hip_bf16.h>

#define BATCH 16
#define NPTS  4096
#define NSAMP 1024   // S = N * 0.25
#define KNB   32     // nsample
#define DFEAT 64

#define THREADS  512
#define FPS_PPT  (NPTS / THREADS)   // 8 points per thread per batch
#define NWV      (THREADS / 64)     // 8 waves per block
#define NFPSB    8                  // FPS blocks, 2 batches each
#define NWBLK    248                // worker blocks
#define NWAVES   (NWBLK * NWV)      // 1984 worker waves
#define NTASK    (BATCH * NSAMP)    // 16384 (b, sq) tasks
#define TAG_BASE 0xC0FFEE00u

// LDS layout (FPS view), bytes:
#define SCA_OFF  0        // float4[4096]  64 KB  coords batch A
#define SCB_OFF  65536    // float4[4096]  64 KB  coords batch B
#define STAX_OFF 131072   // float[1024] x3       staging batch A
#define STAY_OFF 135168
#define STAZ_OFF 139264
#define STBX_OFF 143360   // staging batch B
#define STBY_OFF 147456
#define STBZ_OFF 151552
#define PW_OFF   155648   // u64[2][16] (par, 8*batch+wid)
#define SMEM_SZ  155904

// ---------------------------------------------------------------------------
// DPP wave64 max-reduce round on packed u64 key (key-only).
// Key = (f32_bits(value) << 32) | ~idx : max key == max value, ties -> min idx.
// ---------------------------------------------------------------------------
template <int CTRL, int RMASK>
__device__ __forceinline__ void dpp_round(unsigned long long& key) {
    const int klo = (int)(unsigned)key;
    const int khi = (int)(unsigned)(key >> 32);
    const int tlo = __builtin_amdgcn_update_dpp(klo, klo, CTRL, RMASK, 0xF, false);
    const int thi = __builtin_amdgcn_update_dpp(khi, khi, CTRL, RMASK, 0xF, false);
    const unsigned long long tk =
        ((unsigned long long)(unsigned)thi << 32) | (unsigned)tlo;
    if (tk > key) key = tk;
}

__device__ __forceinline__ void pub_store(unsigned long long* p, unsigned long long v) {
    __hip_atomic_store(p, v, __ATOMIC_RELAXED, __HIP_MEMORY_SCOPE_AGENT);
}
__device__ __forceinline__ unsigned long long pub_load(const unsigned long long* p) {
    return __hip_atomic_load(p, __ATOMIC_RELAXED, __HIP_MEMORY_SCOPE_AGENT);
}

// Barrier waiting only on LDS ops (publish stores stay in flight).
__device__ __forceinline__ void barrier_lds_only() {
    asm volatile("s_waitcnt lgkmcnt(0)" ::: "memory");
    __builtin_amdgcn_s_barrier();
}

// combine 8 wave partials (2x ulong2 pairs) -> max key, tree order
__device__ __forceinline__ unsigned long long combine8(const unsigned long long* p) {
    const ulong2 p01 = *(const ulong2*)&p[0];
    const ulong2 p23 = *(const ulong2*)&p[2];
    const ulong2 p45 = *(const ulong2*)&p[4];
    const ulong2 p67 = *(const ulong2*)&p[6];
    unsigned long long t0 = p01.x > p01.y ? p01.x : p01.y;
    unsigned long long t1 = p23.x > p23.y ? p23.x : p23.y;
    unsigned long long t2 = p45.x > p45.y ? p45.x : p45.y;
    unsigned long long t3 = p67.x > p67.y ? p67.x : p67.y;
    t0 = t0 > t1 ? t0 : t1;
    t2 = t2 > t3 ? t2 : t3;
    return t0 > t2 ? t0 : t2;
}

// ---------------------------------------------------------------------------
// Fused kernel, 512 threads/block, 256 blocks (1/CU).
// Blocks 0..7: FPS for TWO batches each (2*bid, 2*bid+1). The two serial
// chains share one barrier + one latency shadow per step: dist loops and DPP
// reduces of A and B interleave (independent), partials land in one LDS
// buffer, single barrier, two combines + two broadcast centroid reads.
// Per-step cost ~ max(2xVALU, latency) instead of 2x(VALU+latency).
// Blocks 8..255: workers (8 waves each) -- lane-0 poll + wave broadcast,
// ball query + gather + MLP + maxpool per (b, sq) task, sq-major order.
// ---------------------------------------------------------------------------
__global__ __launch_bounds__(THREADS) void fused_kernel(
    const float* __restrict__ xyz, const float* __restrict__ features,
    const float* __restrict__ W1, const float* __restrict__ b1,
    const float* __restrict__ W2, const float* __restrict__ b2,
    float* __restrict__ out_xyz, float* __restrict__ out_pts,
    unsigned long long* __restrict__ pub) {

    __shared__ alignas(16) unsigned char smem[SMEM_SZ];
    const int bid  = blockIdx.x;
    const int tid  = threadIdx.x;
    const int lane = tid & 63;
    const int wid  = tid >> 6;

    if (bid < NFPSB) {
        // ===================== FPS: two batches per block ==================
        const int bA = 2 * bid, bB = 2 * bid + 1;
        float4* scA = (float4*)(smem + SCA_OFF);
        float4* scB = (float4*)(smem + SCB_OFF);
        float* stAX = (float*)(smem + STAX_OFF);
        float* stAY = (float*)(smem + STAY_OFF);
        float* stAZ = (float*)(smem + STAZ_OFF);
        float* stBX = (float*)(smem + STBX_OFF);
        float* stBY = (float*)(smem + STBY_OFF);
        float* stBZ = (float*)(smem + STBZ_OFF);
        unsigned long long* pwb = (unsigned long long*)(smem + PW_OFF);

        float pxA[FPS_PPT], pyA[FPS_PPT], pzA[FPS_PPT], mdA[FPS_PPT];
        float pxB[FPS_PPT], pyB[FPS_PPT], pzB[FPS_PPT], mdB[FPS_PPT];
        const float* baseA = xyz + (size_t)bA * NPTS * 3;
        const float* baseB = xyz + (size_t)bB * NPTS * 3;
#pragma unroll
        for (int j = 0; j < FPS_PPT; j++) {
            const int i = j * THREADS + tid;
            float x = baseA[i * 3 + 0], y = baseA[i * 3 + 1], z = baseA[i * 3 + 2];
            scA[i] = make_float4(x, y, z, 0.0f);
            pxA[j] = x; pyA[j] = y; pzA[j] = z; mdA[j] = 1e10f;
            x = baseB[i * 3 + 0]; y = baseB[i * 3 + 1]; z = baseB[i * 3 + 2];
            scB[i] = make_float4(x, y, z, 0.0f);
            pxB[j] = x; pyB[j] = y; pzB[j] = z; mdB[j] = 1e10f;
        }

        float cxA = baseA[0], cyA = baseA[1], czA = baseA[2];
        float cxB = baseB[0], cyB = baseB[1], czB = baseB[2];
        unsigned long long* pbA = pub + (size_t)bA * NSAMP * 3;
        unsigned long long* pbB = pub + (size_t)bB * NSAMP * 3;
        if (tid == 0) {
            stAX[0] = cxA; stAY[0] = cyA; stAZ[0] = czA;
            stBX[0] = cxB; stBY[0] = cyB; stBZ[0] = czB;
            pub_store(&pbA[0], ((unsigned long long)__float_as_uint(cxA) << 32) | (TAG_BASE + 0));
            pub_store(&pbA[1], ((unsigned long long)__float_as_uint(cyA) << 32) | (TAG_BASE + 0));
            pub_store(&pbA[2], ((unsigned long long)__float_as_uint(czA) << 32) | (TAG_BASE + 0));
            pub_store(&pbB[0], ((unsigned long long)__float_as_uint(cxB) << 32) | (TAG_BASE + 0));
            pub_store(&pbB[1], ((unsigned long long)__float_as_uint(cyB) << 32) | (TAG_BASE + 0));
            pub_store(&pbB[2], ((unsigned long long)__float_as_uint(czB) << 32) | (TAG_BASE + 0));
        }
        __syncthreads();

        for (int s = 1; s < NSAMP; s++) {
            // ---- dist + thread-argmax, batch A ----
            float bestA = -1.0f; int bjA = 0;
#pragma unroll
            for (int j = 0; j < FPS_PPT; j++) {
                const float dx = pxA[j] - cxA;
                const float dy = pyA[j] - cyA;
                const float dz = pzA[j] - czA;
                const float d = __fadd_rn(__fadd_rn(__fmul_rn(dx, dx), __fmul_rn(dy, dy)),
                                          __fmul_rn(dz, dz));
                const float m = fminf(mdA[j], d);
                mdA[j] = m;
                if (m > bestA) { bestA = m; bjA = j; }
            }
            // ---- dist + thread-argmax, batch B ----
            float bestB = -1.0f; int bjB = 0;
#pragma unroll
            for (int j = 0; j < FPS_PPT; j++) {
                const float dx = pxB[j] - cxB;
                const float dy = pyB[j] - cyB;
                const float dz = pzB[j] - czB;
                const float d = __fadd_rn(__fadd_rn(__fmul_rn(dx, dx), __fmul_rn(dy, dy)),
                                          __fmul_rn(dz, dz));
                const float m = fminf(mdB[j], d);
                mdB[j] = m;
                if (m > bestB) { bestB = m; bjB = j; }
            }
            const int biA = (bjA << 9) | tid;
            const int biB = (bjB << 9) | tid;
            unsigned long long keyA =
                ((unsigned long long)__float_as_uint(bestA) << 32) | (unsigned)(~biA);
            unsigned long long keyB =
                ((unsigned long long)__float_as_uint(bestB) << 32) | (unsigned)(~biB);
            // interleaved DPP reduces: independent chains pipeline
            dpp_round<0x111, 0xF>(keyA); dpp_round<0x111, 0xF>(keyB);
            dpp_round<0x112, 0xF>(keyA); dpp_round<0x112, 0xF>(keyB);
            dpp_round<0x114, 0xF>(keyA); dpp_round<0x114, 0xF>(keyB);
            dpp_round<0x118, 0xF>(keyA); dpp_round<0x118, 0xF>(keyB);
            dpp_round<0x142, 0xA>(keyA); dpp_round<0x142, 0xA>(keyB);
            dpp_round<0x143, 0xC>(keyA); dpp_round<0x143, 0xC>(keyB);

            const int par = s & 1;
            if (lane == 63) {
                pwb[par * 16 + wid]     = keyA;
                pwb[par * 16 + 8 + wid] = keyB;
            }
            barrier_lds_only();   // ONE barrier serves both chains
            const unsigned long long bkA = combine8(&pwb[par * 16]);
            const unsigned long long bkB = combine8(&pwb[par * 16 + 8]);
            const int bixA = (int)(~(unsigned)bkA);
            const int bixB = (int)(~(unsigned)bkB);

            const float4 cA = scA[bixA];   // two broadcast b128 reads pipeline
            const float4 cB = scB[bixB];
            cxA = cA.x; cyA = cA.y; czA = cA.z;
            cxB = cB.x; cyB = cB.y; czB = cB.z;
            if (tid == 0) {
                stAX[s] = cxA; stAY[s] = cyA; stAZ[s] = czA;
                pub_store(&pbA[3 * s + 0], ((unsigned long long)__float_as_uint(cxA) << 32) | (TAG_BASE + s));
                pub_store(&pbA[3 * s + 1], ((unsigned long long)__float_as_uint(cyA) << 32) | (TAG_BASE + s));
                pub_store(&pbA[3 * s + 2], ((unsigned long long)__float_as_uint(czA) << 32) | (TAG_BASE + s));
            }
            if (tid == 64) {   // wave 1 lane 0 publishes B in parallel
                stBX[s] = cxB; stBY[s] = cyB; stBZ[s] = czB;
                pub_store(&pbB[3 * s + 0], ((unsigned long long)__float_as_uint(cxB) << 32) | (TAG_BASE + s));
                pub_store(&pbB[3 * s + 1], ((unsigned long long)__float_as_uint(cyB) << 32) | (TAG_BASE + s));
                pub_store(&pbB[3 * s + 2], ((unsigned long long)__float_as_uint(czB) << 32) | (TAG_BASE + s));
            }
        }

        __syncthreads();
        float* obA = out_xyz + (size_t)bA * 3 * NSAMP;
        float* obB = out_xyz + (size_t)bB * 3 * NSAMP;
        for (int i = tid; i < NSAMP; i += THREADS) {
            obA[0 * NSAMP + i] = stAX[i];
            obA[1 * NSAMP + i] = stAY[i];
            obA[2 * NSAMP + i] = stAZ[i];
            obB[0 * NSAMP + i] = stBX[i];
            obB[1 * NSAMP + i] = stBY[i];
            obB[2 * NSAMP + i] = stBZ[i];
        }
    } else {
        // ========================== WORKER (8 waves) =======================
        float (*xls)[KNB][DFEAT] = (float (*)[KNB][DFEAT])smem;          // 64 KB
        float (*h1s)[DFEAT]      = (float (*)[DFEAT])(smem + 65536);     // 2 KB
        int   (*gl)[KNB]         = (int (*)[KNB])(smem + 65536 + 2048);  // 1 KB

        float w1r[64], w2ra[64], w2rb[64];
        {
            const float4* W1v = (const float4*)(W1 + (size_t)lane * 64);
            const float4* W2a = (const float4*)(W2 + (size_t)lane * 64);
            const float4* W2b = (const float4*)(W2 + (size_t)(lane + 64) * 64);
#pragma unroll
            for (int i = 0; i < 16; i++) {
                float4 v = W1v[i];
                w1r[4 * i] = v.x; w1r[4 * i + 1] = v.y; w1r[4 * i + 2] = v.z; w1r[4 * i + 3] = v.w;
                v = W2a[i];
                w2ra[4 * i] = v.x; w2ra[4 * i + 1] = v.y; w2ra[4 * i + 2] = v.z; w2ra[4 * i + 3] = v.w;
                v = W2b[i];
                w2rb[4 * i] = v.x; w2rb[4 * i + 1] = v.y; w2rb[4 * i + 2] = v.z; w2rb[4 * i + 3] = v.w;
            }
        }
        const float b1r  = b1[lane];
        const float b2ra = b2[lane];
        const float b2rb = b2[lane + 64];

        const int gwave = (bid - NFPSB) * NWV + wid;
        for (int t = gwave; t < NTASK; t += NWAVES) {
            const int sq = t >> 4;    // sq-major: waves sweep s together
            const int b  = t & 15;

            const unsigned long long* pp = pub + ((size_t)b * NSAMP + sq) * 3;
            const unsigned exp_tag = TAG_BASE + sq;
            float pxf = 0.0f, pyf = 0.0f, pzf = 0.0f;
            if (lane == 0) {
                unsigned long long w0, w1, w2;
                for (;;) {
                    w0 = pub_load(&pp[0]);
                    w1 = pub_load(&pp[1]);
                    w2 = pub_load(&pp[2]);
                    if ((unsigned)w0 == exp_tag && (unsigned)w1 == exp_tag &&
                        (unsigned)w2 == exp_tag) break;
                    __builtin_amdgcn_s_sleep(2);
                }
                pxf = __uint_as_float((unsigned)(w0 >> 32));
                pyf = __uint_as_float((unsigned)(w1 >> 32));
                pzf = __uint_as_float((unsigned)(w2 >> 32));
            }
            const float cx = __shfl(pxf, 0);
            const float cy = __shfl(pyf, 0);
            const float cz = __shfl(pzf, 0);

            const float* base = xyz + (size_t)b * NPTS * 3;
            const float r2 = 0.04f;
            int cnt = 0;
            int firstCand = 0x7fffffff;
            for (int bp = 0; bp < NPTS && cnt < KNB; bp += 64) {
                const int p = bp + lane;
                const float dx = base[p * 3 + 0] - cx;
                const float dy = base[p * 3 + 1] - cy;
                const float dz = base[p * 3 + 2] - cz;
                const float d = __fadd_rn(__fadd_rn(__fmul_rn(dx, dx), __fmul_rn(dy, dy)),
                                          __fmul_rn(dz, dz));
                const bool ok = !(d > r2);
                const unsigned long long m = __ballot(ok);
                const int rank = cnt + (int)__popcll(m & ((1ull << lane) - 1ull));
                if (ok && rank < KNB) gl[wid][rank] = p;
                if (ok && rank == 0) firstCand = p;
                cnt += (int)__popcll(m);
            }
            const int found = cnt < KNB ? cnt : KNB;
            if (found < KNB) {
#pragma unroll
                for (int off = 32; off > 0; off >>= 1) {
                    const int o = __shfl_xor(firstCand, off);
                    firstCand = o < firstCand ? o : firstCand;
                }
                for (int r = found + lane; r < KNB; r += 64) gl[wid][r] = firstCand;
            }
            int gi = 0;
            if (lane < KNB) gi = gl[wid][lane];

            const float* fb = features + (size_t)b * NPTS * DFEAT;
            for (int k = 0; k < KNB; k++) {
                const int idxk = __shfl(gi, k);
                xls[wid][k][lane] = fb[(size_t)idxk * DFEAT + lane];
            }

            float m0 = 0.0f, m1 = 0.0f;
            for (int k = 0; k < KNB; k++) {
                float acc = b1r;
                const float4* xk = (const float4*)xls[wid][k];
#pragma unroll
                for (int i = 0; i < 16; i++) {
                    const float4 v = xk[i];
                    acc = fmaf(v.x, w1r[4 * i], acc);
                    acc = fmaf(v.y, w1r[4 * i + 1], acc);
                    acc = fmaf(v.z, w1r[4 * i + 2], acc);
                    acc = fmaf(v.w, w1r[4 * i + 3], acc);
                }
                h1s[wid][lane] = fmaxf(acc, 0.0f);
                float a0 = b2ra, a1 = b2rb;
                const float4* hv4 = (const float4*)h1s[wid];
#pragma unroll
                for (int i = 0; i < 16; i++) {
                    const float4 v = hv4[i];
                    a0 = fmaf(v.x, w2ra[4 * i], a0);
                    a0 = fmaf(v.y, w2ra[4 * i + 1], a0);
                    a0 = fmaf(v.z, w2ra[4 * i + 2], a0);
                    a0 = fmaf(v.w, w2ra[4 * i + 3], a0);
                    a1 = fmaf(v.x, w2rb[4 * i], a1);
                    a1 = fmaf(v.y, w2rb[4 * i + 1], a1);
                    a1 = fmaf(v.z, w2rb[4 * i + 2], a1);
                    a1 = fmaf(v.w, w2rb[4 * i + 3], a1);
                }
                m0 = fmaxf(m0, fmaxf(a0, 0.0f));
                m1 = fmaxf(m1, fmaxf(a1, 0.0f));
            }

            out_pts[(size_t)b * 128 * NSAMP + (size_t)lane * NSAMP + sq]        = m0;
            out_pts[(size_t)b * 128 * NSAMP + (size_t)(lane + 64) * NSAMP + sq] = m1;
        }
    }
}

extern "C" void kernel_launch(void* const* d_in, const int* in_sizes, int n_in,
                              void* d_out, int out_size, void* d_ws, size_t ws_size,
                              hipStream_t stream) {
    const float* xyz      = (const float*)d_in[0];
    const float* features = (const float*)d_in[1];
    const float* W1       = (const float*)d_in[2];
    const float* b1       = (const float*)d_in[3];
    const float* W2       = (const float*)d_in[4];
    const float* b2       = (const float*)d_in[5];

    float* out_xyz = (float*)d_out;                                  // [B,3,S]
    float* out_pts = (float*)d_out + (size_t)BATCH * 3 * NSAMP;      // [B,128,S]

    unsigned long long* pub = (unsigned long long*)d_ws;             // [B,S,3]

    fused_kernel<<<NFPSB + NWBLK, THREADS, 0, stream>>>(
        xyz, features, W1, b1, W2, b2, out_xyz, out_pts, pub);
}

// Round 18
// 667.285 us; speedup vs baseline: 1.8724x; 1.8724x over previous
//
#include <hip/hip_runtime.h>
#include <hip/hip_bf16.h>

#define BATCH 16
#define NPTS  4096
#define NSAMP 1024   // S = N * 0.25
#define KNB   32     // nsample
#define DFEAT 64

#define THREADS  512
#define FPS_PPT  (NPTS / THREADS)   // 8 points per thread
#define NWV      (THREADS / 64)     // 8 waves per block
#define NWBLK    240                // worker blocks
#define NWAVES   (NWBLK * NWV)      // 1920 worker waves
#define NTASK    (BATCH * NSAMP)    // 16384 (b, sq) tasks
#define TAG_BASE 0xC0FFEE00u

// ---------------------------------------------------------------------------
// DPP wave64 max-reduce round on packed u64 key (key-only).
// Key = (f32_bits(value) << 32) | ~idx : max key == max value, ties -> min idx.
// ---------------------------------------------------------------------------
template <int CTRL, int RMASK>
__device__ __forceinline__ void dpp_round(unsigned long long& key) {
    const int klo = (int)(unsigned)key;
    const int khi = (int)(unsigned)(key >> 32);
    const int tlo = __builtin_amdgcn_update_dpp(klo, klo, CTRL, RMASK, 0xF, false);
    const int thi = __builtin_amdgcn_update_dpp(khi, khi, CTRL, RMASK, 0xF, false);
    const unsigned long long tk =
        ((unsigned long long)(unsigned)thi << 32) | (unsigned)tlo;
    if (tk > key) key = tk;
}

__device__ __forceinline__ void pub_store(unsigned long long* p, unsigned long long v) {
    __hip_atomic_store(p, v, __ATOMIC_RELAXED, __HIP_MEMORY_SCOPE_AGENT);
}
__device__ __forceinline__ unsigned long long pub_load(const unsigned long long* p) {
    return __hip_atomic_load(p, __ATOMIC_RELAXED, __HIP_MEMORY_SCOPE_AGENT);
}

// Barrier waiting only on LDS ops (publish stores stay in flight).
__device__ __forceinline__ void barrier_lds_only() {
    asm volatile("s_waitcnt lgkmcnt(0)" ::: "memory");
    __builtin_amdgcn_s_barrier();
}

// ---------------------------------------------------------------------------
// Fused kernel, 512 threads/block (R12 structure frozen). Blocks 0..15: FPS.
// Publish/staging done by lanes 0..2 as ONE coalesced global store (24 B,
// 3 active lanes) + ONE ds_write, instead of 3+3 serial ops from tid0 --
// removes ~4 issue slots + outstanding-store tails from the serial chain.
// Blocks 16..255: workers (8 waves), lane-0 poll + wave broadcast.
// ---------------------------------------------------------------------------
__global__ __launch_bounds__(THREADS) void fused_kernel(
    const float* __restrict__ xyz, const float* __restrict__ features,
    const float* __restrict__ W1, const float* __restrict__ b1,
    const float* __restrict__ W2, const float* __restrict__ b2,
    float* __restrict__ out_xyz, float* __restrict__ out_pts,
    unsigned long long* __restrict__ pub) {

    __shared__ alignas(16) unsigned char smem[65536 + 12288 + 128];
    const int bid  = blockIdx.x;
    const int tid  = threadIdx.x;
    const int lane = tid & 63;
    const int wid  = tid >> 6;

    if (bid < BATCH) {
        // =================== FPS (R12 form, 8 waves) =======================
        float4* sc = (float4*)smem;                          // 64 KB coords
        float* st  = (float*)(smem + 65536);                 // 12 KB staging: [3][NSAMP]
        unsigned long long* pw = (unsigned long long*)(smem + 65536 + 12288);

        float px[FPS_PPT], py[FPS_PPT], pz[FPS_PPT], md[FPS_PPT];
        const float* base = xyz + (size_t)bid * NPTS * 3;
#pragma unroll
        for (int j = 0; j < FPS_PPT; j++) {
            const int i = j * THREADS + tid;
            const float x = base[i * 3 + 0];
            const float y = base[i * 3 + 1];
            const float z = base[i * 3 + 2];
            sc[i] = make_float4(x, y, z, 0.0f);
            px[j] = x; py[j] = y; pz[j] = z;
            md[j] = 1e10f;
        }

        float cx = base[0], cy = base[1], cz = base[2];
        unsigned long long* pb = pub + (size_t)bid * NSAMP * 3;
        if (tid < 3) {
            const float v = tid == 0 ? cx : (tid == 1 ? cy : cz);
            st[tid * NSAMP + 0] = v;
            pub_store(&pb[tid],
                      ((unsigned long long)__float_as_uint(v) << 32) | (TAG_BASE + 0));
        }
        __syncthreads();

        for (int s = 1; s < NSAMP; s++) {
            float best = -1.0f;
            int   bj   = 0;
#pragma unroll
            for (int j = 0; j < FPS_PPT; j++) {
                const float dx = px[j] - cx;
                const float dy = py[j] - cy;
                const float dz = pz[j] - cz;
                // match reference rounding: no fma contraction
                const float d = __fadd_rn(__fadd_rn(__fmul_rn(dx, dx), __fmul_rn(dy, dy)),
                                          __fmul_rn(dz, dz));
                const float m = fminf(md[j], d);
                md[j] = m;
                if (m > best) { best = m; bj = j; }
            }
            const int bi = (bj << 9) | tid;    // j*512 + tid (disjoint bits)
            unsigned long long key =
                ((unsigned long long)__float_as_uint(best) << 32) | (unsigned)(~bi);
            dpp_round<0x111, 0xF>(key);
            dpp_round<0x112, 0xF>(key);
            dpp_round<0x114, 0xF>(key);
            dpp_round<0x118, 0xF>(key);
            dpp_round<0x142, 0xA>(key);
            dpp_round<0x143, 0xC>(key);

            const int par = s & 1;
            if (lane == 63) pw[par * NWV + wid] = key;
            barrier_lds_only();
            const ulong2 p01 = *(const ulong2*)&pw[par * NWV + 0];
            const ulong2 p23 = *(const ulong2*)&pw[par * NWV + 2];
            const ulong2 p45 = *(const ulong2*)&pw[par * NWV + 4];
            const ulong2 p67 = *(const ulong2*)&pw[par * NWV + 6];
            unsigned long long bk = p01.x;
            if (p01.y > bk) bk = p01.y;
            if (p23.x > bk) bk = p23.x;
            if (p23.y > bk) bk = p23.y;
            if (p45.x > bk) bk = p45.x;
            if (p45.y > bk) bk = p45.y;
            if (p67.x > bk) bk = p67.x;
            if (p67.y > bk) bk = p67.y;
            const int bix = (int)(~(unsigned)bk);

            const float4 c = sc[bix];
            cx = c.x; cy = c.y; cz = c.z;
            // 3-lane publish: one ds_write + one coalesced 24B global store
            if (tid < 3) {
                const float v = tid == 0 ? cx : (tid == 1 ? cy : cz);
                st[tid * NSAMP + s] = v;
                pub_store(&pb[3 * s + tid],
                          ((unsigned long long)__float_as_uint(v) << 32) |
                          (TAG_BASE + (unsigned)s));
            }
        }

        __syncthreads();
        float* ob = out_xyz + (size_t)bid * 3 * NSAMP;
        for (int i = tid; i < NSAMP; i += THREADS) {
            ob[0 * NSAMP + i] = st[0 * NSAMP + i];
            ob[1 * NSAMP + i] = st[1 * NSAMP + i];
            ob[2 * NSAMP + i] = st[2 * NSAMP + i];
        }
    } else {
        // ========================== WORKER (8 waves) =======================
        float (*xls)[KNB][DFEAT] = (float (*)[KNB][DFEAT])smem;          // 64 KB
        float (*h1s)[DFEAT]      = (float (*)[DFEAT])(smem + 65536);     // 2 KB
        int   (*gl)[KNB]         = (int (*)[KNB])(smem + 65536 + 2048);  // 1 KB

        // weights -> registers (once per wave)
        float w1r[64], w2ra[64], w2rb[64];
        {
            const float4* W1v = (const float4*)(W1 + (size_t)lane * 64);
            const float4* W2a = (const float4*)(W2 + (size_t)lane * 64);
            const float4* W2b = (const float4*)(W2 + (size_t)(lane + 64) * 64);
#pragma unroll
            for (int i = 0; i < 16; i++) {
                float4 v = W1v[i];
                w1r[4 * i] = v.x; w1r[4 * i + 1] = v.y; w1r[4 * i + 2] = v.z; w1r[4 * i + 3] = v.w;
                v = W2a[i];
                w2ra[4 * i] = v.x; w2ra[4 * i + 1] = v.y; w2ra[4 * i + 2] = v.z; w2ra[4 * i + 3] = v.w;
                v = W2b[i];
                w2rb[4 * i] = v.x; w2rb[4 * i + 1] = v.y; w2rb[4 * i + 2] = v.z; w2rb[4 * i + 3] = v.w;
            }
        }
        const float b1r  = b1[lane];
        const float b2ra = b2[lane];
        const float b2rb = b2[lane + 64];

        const int gwave = (bid - BATCH) * NWV + wid;
        for (int t = gwave; t < NTASK; t += NWAVES) {
            const int sq = t >> 4;    // sq-major: waves sweep s together
            const int b  = t & 15;

            // ---- poll centroid: LANE 0 ONLY, then wave-broadcast ----------
            const unsigned long long* pp = pub + ((size_t)b * NSAMP + sq) * 3;
            const unsigned exp_tag = TAG_BASE + sq;
            float pxf = 0.0f, pyf = 0.0f, pzf = 0.0f;
            if (lane == 0) {
                unsigned long long w0, w1, w2;
                for (;;) {
                    w0 = pub_load(&pp[0]);
                    w1 = pub_load(&pp[1]);
                    w2 = pub_load(&pp[2]);
                    if ((unsigned)w0 == exp_tag && (unsigned)w1 == exp_tag &&
                        (unsigned)w2 == exp_tag) break;
                    __builtin_amdgcn_s_sleep(2);
                }
                pxf = __uint_as_float((unsigned)(w0 >> 32));
                pyf = __uint_as_float((unsigned)(w1 >> 32));
                pzf = __uint_as_float((unsigned)(w2 >> 32));
            }
            const float cx = __shfl(pxf, 0);
            const float cy = __shfl(pyf, 0);
            const float cz = __shfl(pzf, 0);

            // ---- ball query into wave-local LDS slice ----
            const float* base = xyz + (size_t)b * NPTS * 3;
            const float r2 = 0.04f;
            int cnt = 0;
            int firstCand = 0x7fffffff;
            for (int bp = 0; bp < NPTS && cnt < KNB; bp += 64) {
                const int p = bp + lane;
                const float dx = base[p * 3 + 0] - cx;
                const float dy = base[p * 3 + 1] - cy;
                const float dz = base[p * 3 + 2] - cz;
                const float d = __fadd_rn(__fadd_rn(__fmul_rn(dx, dx), __fmul_rn(dy, dy)),
                                          __fmul_rn(dz, dz));
                const bool ok = !(d > r2);
                const unsigned long long m = __ballot(ok);
                const int rank = cnt + (int)__popcll(m & ((1ull << lane) - 1ull));
                if (ok && rank < KNB) gl[wid][rank] = p;
                if (ok && rank == 0) firstCand = p;
                cnt += (int)__popcll(m);
            }
            const int found = cnt < KNB ? cnt : KNB;
            if (found < KNB) {
#pragma unroll
                for (int off = 32; off > 0; off >>= 1) {
                    const int o = __shfl_xor(firstCand, off);
                    firstCand = o < firstCand ? o : firstCand;
                }
                for (int r = found + lane; r < KNB; r += 64) gl[wid][r] = firstCand;
            }
            int gi = 0;
            if (lane < KNB) gi = gl[wid][lane];

            // ---- gather 32 neighbor feature rows into LDS ----
            const float* fb = features + (size_t)b * NPTS * DFEAT;
            for (int k = 0; k < KNB; k++) {
                const int idxk = __shfl(gi, k);
                xls[wid][k][lane] = fb[(size_t)idxk * DFEAT + lane];
            }

            // ---- MLP + maxpool ----
            float m0 = 0.0f, m1 = 0.0f;
            for (int k = 0; k < KNB; k++) {
                float acc = b1r;
                const float4* xk = (const float4*)xls[wid][k];
#pragma unroll
                for (int i = 0; i < 16; i++) {
                    const float4 v = xk[i];
                    acc = fmaf(v.x, w1r[4 * i], acc);
                    acc = fmaf(v.y, w1r[4 * i + 1], acc);
                    acc = fmaf(v.z, w1r[4 * i + 2], acc);
                    acc = fmaf(v.w, w1r[4 * i + 3], acc);
                }
                h1s[wid][lane] = fmaxf(acc, 0.0f);
                float a0 = b2ra, a1 = b2rb;
                const float4* hv4 = (const float4*)h1s[wid];
#pragma unroll
                for (int i = 0; i < 16; i++) {
                    const float4 v = hv4[i];
                    a0 = fmaf(v.x, w2ra[4 * i], a0);
                    a0 = fmaf(v.y, w2ra[4 * i + 1], a0);
                    a0 = fmaf(v.z, w2ra[4 * i + 2], a0);
                    a0 = fmaf(v.w, w2ra[4 * i + 3], a0);
                    a1 = fmaf(v.x, w2rb[4 * i], a1);
                    a1 = fmaf(v.y, w2rb[4 * i + 1], a1);
                    a1 = fmaf(v.z, w2rb[4 * i + 2], a1);
                    a1 = fmaf(v.w, w2rb[4 * i + 3], a1);
                }
                m0 = fmaxf(m0, fmaxf(a0, 0.0f));
                m1 = fmaxf(m1, fmaxf(a1, 0.0f));
            }

            out_pts[(size_t)b * 128 * NSAMP + (size_t)lane * NSAMP + sq]        = m0;
            out_pts[(size_t)b * 128 * NSAMP + (size_t)(lane + 64) * NSAMP + sq] = m1;
        }
    }
}

extern "C" void kernel_launch(void* const* d_in, const int* in_sizes, int n_in,
                              void* d_out, int out_size, void* d_ws, size_t ws_size,
                              hipStream_t stream) {
    const float* xyz      = (const float*)d_in[0];
    const float* features = (const float*)d_in[1];
    const float* W1       = (const float*)d_in[2];
    const float* b1       = (const float*)d_in[3];
    const float* W2       = (const float*)d_in[4];
    const float* b2       = (const float*)d_in[5];

    float* out_xyz = (float*)d_out;                                  // [B,3,S]
    float* out_pts = (float*)d_out + (size_t)BATCH * 3 * NSAMP;      // [B,128,S]

    unsigned long long* pub = (unsigned long long*)d_ws;             // [B,S,3]

    fused_kernel<<<BATCH + NWBLK, THREADS, 0, stream>>>(
        xyz, features, W1, b1, W2, b2, out_xyz, out_pts, pub);
}